// Round 3
// baseline (1679.450 us; speedup 1.0000x reference)
//
#include <hip/hip_runtime.h>
#include <hip/hip_bf16.h>

using bf16 = __hip_bfloat16;
using short8 = __attribute__((ext_vector_type(8))) short;
using float4v = __attribute__((ext_vector_type(4))) float;

#define BM 64
#define BN 64
#define BK 32
#define LDSP 48  // padded LDS row (shorts)

__device__ inline short f2b(float x) {
  bf16 h = __float2bfloat16(x);
  return __builtin_bit_cast(short, h);
}

// load 8 contiguous elements at element-offset eoff; F32: convert f32->bf16
template<int F32>
__device__ inline short8 ld8e(const void* base, long eoff) {
  short8 r;
  if constexpr (F32) {
    const float* f = (const float*)base + eoff;
    #pragma unroll
    for (int i = 0; i < 8; ++i) r[i] = f2b(f[i]);
  } else {
    r = *(const short8*)((const short*)base + eoff);
  }
  return r;
}

// A flavors: 0: off=m*lda+k ; 1: off=k*lda+m (transpose-stage)
//            2: off=(k/96)*9216+m*96+(k%96) (height-chunked)
// B flavors: 0: off=n*ldb+k ; 1: off=k*ldb+n (transpose-stage)
//            2: off=(k/96)*9216+n*96+(k%96) ; 3: off=(n/96)*9216+k*96+(n%96)
// EPI: 0: f32 atomicAdd C[row*ldc+col]
//      1: bf16 store (+f32 bias[row] if bias)
//      2: f32 x[col*96+row] += beta*v ; 3: f32 x[(col/96)*9216+row*96+col%96] += beta*v
//      4: f32 x[row*ldc+col] += beta*v
template<int AF, int BF, int EPI, int AF32, int BF32>
__global__ __launch_bounds__(256) void gemm_k(
    const void* __restrict__ Ag, const void* __restrict__ Bg,
    void* __restrict__ Cv, const float* __restrict__ bias, const float* __restrict__ betaP,
    int M, int N, int K, int lda, int ldb, int ldc,
    long sA, long sB, long sC, int ksplit)
{
  __shared__ short As[BM][LDSP];
  __shared__ short Bs[BN][LDSP];
  const int t = threadIdx.x;
  const int lane = t & 63;
  const int wave = t >> 6;
  const int wm = (wave >> 1) * 32;
  const int wn = (wave & 1) * 32;
  const int fr = lane & 15;
  const int fq = lane >> 4;
  const int bz = blockIdx.z;
  const int batch = bz / ksplit;
  const int kc = bz - batch * ksplit;
  const int Kc = K / ksplit;
  const int k0 = kc * Kc;
  const int tm0 = blockIdx.y * BM;
  const int tn0 = blockIdx.x * BN;
  const long abase = (long)batch * sA;
  const long bbase = (long)batch * sB;

  float4v acc[2][2] = {};
  union V8 { short8 v; short s[8]; };

  for (int kk = 0; kk < Kc; kk += BK) {
    const int kbase = k0 + kk;
    // ---- stage A tile: As[m][k] ----
    if constexpr (AF == 0 || AF == 2) {
      int m = t >> 2;
      int kloc = (t & 3) * 8;
      int gk = kbase + kloc;
      short8 v = {};
      if (tm0 + m < M) {
        long off;
        if constexpr (AF == 0) off = abase + (long)(tm0 + m) * lda + gk;
        else                   off = abase + (long)(gk / 96) * 9216 + (long)(tm0 + m) * 96 + (gk % 96);
        v = ld8e<AF32>(Ag, off);
      }
      *(short8*)&As[m][kloc] = v;
    } else {  // AF == 1: 8 contiguous m at fixed k, scatter to LDS
      int m8 = (t & 7) * 8;
      int k = t >> 3;
      V8 u; u.v = short8{};
      if (tm0 + m8 < M)
        u.v = ld8e<AF32>(Ag, abase + (long)(kbase + k) * lda + tm0 + m8);
      #pragma unroll
      for (int i = 0; i < 8; ++i) As[m8 + i][k] = u.s[i];
    }
    // ---- stage B tile: Bs[n][k] ----
    if constexpr (BF == 0 || BF == 2) {
      int n = t >> 2;
      int kloc = (t & 3) * 8;
      int gk = kbase + kloc;
      short8 v = {};
      if (tn0 + n < N) {
        long off;
        if constexpr (BF == 0) off = bbase + (long)(tn0 + n) * ldb + gk;
        else                   off = bbase + (long)(gk / 96) * 9216 + (long)(tn0 + n) * 96 + (gk % 96);
        v = ld8e<BF32>(Bg, off);
      }
      *(short8*)&Bs[n][kloc] = v;
    } else {  // BF == 1 or 3: 8 contiguous n at fixed k
      int n8 = (t & 7) * 8;
      int k = t >> 3;
      int gn = tn0 + n8;
      V8 u; u.v = short8{};
      if (gn < N) {
        long off;
        if constexpr (BF == 1) off = bbase + (long)(kbase + k) * ldb + gn;
        else                   off = bbase + (long)(gn / 96) * 9216 + (long)(kbase + k) * 96 + (gn % 96);
        u.v = ld8e<BF32>(Bg, off);
      }
      #pragma unroll
      for (int i = 0; i < 8; ++i) Bs[n8 + i][k] = u.s[i];
    }
    __syncthreads();
    short8 af[2], bfv[2];
    #pragma unroll
    for (int i = 0; i < 2; ++i) af[i] = *(const short8*)&As[wm + i * 16 + fr][fq * 8];
    #pragma unroll
    for (int j = 0; j < 2; ++j) bfv[j] = *(const short8*)&Bs[wn + j * 16 + fr][fq * 8];
    #pragma unroll
    for (int i = 0; i < 2; ++i)
      #pragma unroll
      for (int j = 0; j < 2; ++j)
        acc[i][j] = __builtin_amdgcn_mfma_f32_16x16x32_bf16(af[i], bfv[j], acc[i][j], 0, 0, 0);
    __syncthreads();
  }

  float beta = 0.0f;
  if constexpr (EPI >= 2) beta = *betaP;
  const long cb = (long)batch * sC;
  #pragma unroll
  for (int i = 0; i < 2; ++i) {
    #pragma unroll
    for (int j = 0; j < 2; ++j) {
      #pragma unroll
      for (int r = 0; r < 4; ++r) {
        int row = tm0 + wm + i * 16 + fq * 4 + r;
        int col = tn0 + wn + j * 16 + fr;
        if (row < M && col < N) {
          float v = acc[i][j][r];
          if constexpr (EPI == 0) {
            atomicAdd((float*)Cv + cb + (long)row * ldc + col, v);
          } else if constexpr (EPI == 1) {
            if (bias) v += bias[row];
            ((short*)Cv)[cb + (long)row * ldc + col] = f2b(v);
          } else {
            long xi;
            if constexpr (EPI == 2)      xi = cb + (long)col * 96 + row;
            else if constexpr (EPI == 3) xi = cb + (long)(col / 96) * 9216 + (long)row * 96 + (col % 96);
            else                         xi = cb + (long)row * ldc + col;
            float* xp = (float*)Cv;
            xp[xi] += beta * v;
          }
        }
      }
    }
  }
}

// softmax over n cols; logits' = in[row][c] (+ addj[b*n+c]) (+ rowv[row]*colv[c]); out bf16
__global__ __launch_bounds__(256) void softmax_k(
    const float* __restrict__ in, short* __restrict__ out, int n, int rows,
    const float* __restrict__ addj, const float* __restrict__ rowv,
    const float* __restrict__ colv)
{
  int wave = threadIdx.x >> 6;
  int lane = threadIdx.x & 63;
  int row = blockIdx.x * 4 + wave;
  if (row >= rows) return;
  int b = row / n;
  const float* r = in + (long)row * n;
  float rv = rowv ? rowv[row] : 0.0f;
  float vals[4];
  float m = -1e30f;
  #pragma unroll
  for (int i = 0; i < 4; ++i) {
    int c = lane + i * 64;
    float v = -1e30f;
    if (c < n) {
      v = r[c];
      if (addj) v += addj[(long)b * n + c];
      if (colv) v += rv * colv[c];
    }
    vals[i] = v;
    m = fmaxf(m, v);
  }
  #pragma unroll
  for (int off = 32; off > 0; off >>= 1) m = fmaxf(m, __shfl_xor(m, off));
  float s = 0.0f;
  #pragma unroll
  for (int i = 0; i < 4; ++i) {
    int c = lane + i * 64;
    float e = (c < n) ? __expf(vals[i] - m) : 0.0f;
    vals[i] = e;
    s += e;
  }
  #pragma unroll
  for (int off = 32; off > 0; off >>= 1) s += __shfl_xor(s, off);
  float inv = 1.0f / s;
  #pragma unroll
  for (int i = 0; i < 4; ++i) {
    int c = lane + i * 64;
    if (c < n) out[(long)row * n + c] = f2b(vals[i] * inv);
  }
}

// dst[row] = sum_k bf16 src[row*rowlen+k]; one wave per row
__global__ __launch_bounds__(256) void sum_rows_k(
    const short* __restrict__ src, float* __restrict__ dst, int rowlen, int nrows)
{
  int wave = threadIdx.x >> 6;
  int lane = threadIdx.x & 63;
  int row = blockIdx.x * 4 + wave;
  if (row >= nrows) return;
  const short* p = src + (long)row * rowlen;
  float s = 0.0f;
  for (int k = lane; k < rowlen; k += 64)
    s += __bfloat162float(__builtin_bit_cast(bf16, p[k]));
  #pragma unroll
  for (int off = 32; off > 0; off >>= 1) s += __shfl_xor(s, off);
  if (lane == 0) dst[row] = s;
}

// wv[c] = sum_o btheta[o] * Wphi[o*256+c]   (all f32)
__global__ __launch_bounds__(256) void wv_k(
    const float* __restrict__ wphi, const float* __restrict__ btheta, float* __restrict__ wv)
{
  int c = threadIdx.x;
  float s = 0.0f;
  for (int o = 0; o < 256; ++o) s += btheta[o] * wphi[o * 256 + c];
  wv[c] = s;
}

// vfull[b][hw] = sum_c wv[c] * x_f32[b][c*9216+hw]
__global__ __launch_bounds__(256) void vfull_k(
    const float* __restrict__ x, const float* __restrict__ wv, float* __restrict__ vf)
{
  long idx = (long)blockIdx.x * 256 + threadIdx.x;   // 16*9216
  int b = (int)(idx / 9216);
  int hw = (int)(idx % 9216);
  const float* p = x + (long)b * 2359296 + hw;
  float s = 0.0f;
  for (int c = 0; c < 256; ++c) s += wv[c] * p[(long)c * 9216];
  vf[idx] = s;
}

// axis 0 (width): r[b][j]=sum_h vf[b][h*96+j]; axis 1 (height): r[b][j]=sum_w vf[b][j*96+w]
__global__ __launch_bounds__(256) void rsum_k(
    const float* __restrict__ vf, float* __restrict__ r, int axis)
{
  int idx = blockIdx.x * 256 + threadIdx.x;   // 16*96
  int b = idx / 96;
  int j = idx % 96;
  const float* p = vf + (long)b * 9216;
  float s = 0.0f;
  if (axis == 0) { for (int h = 0; h < 96; ++h) s += p[h * 96 + j]; }
  else           { for (int w = 0; w < 96; ++w) s += p[j * 96 + w]; }
  r[idx] = s;
}

extern "C" void kernel_launch(void* const* d_in, const int* in_sizes, int n_in,
                              void* d_out, int out_size, void* d_ws, size_t ws_size,
                              hipStream_t stream)
{
  const long TS = 37748736L;   // 16*256*96*96
  const long BS = 2359296L;    // 256*96*96

  float* x = (float*)d_out;                       // f32 state, updated in place
  short* big   = (short*)d_ws;                    // 75.5 MB bf16: Y / Theta / G
  float* attf  = (float*)(big + TS);              // 4 MB
  short* attb  = (short*)(attf + 1048576);        // 2 MB bf16
  short* Zbuf  = attb + 1048576;                  // 2 MB bf16 [16,256,256]
  short* Mbuf  = Zbuf + 1048576;                  // 128 KB bf16 [256,256]
  float* vfull = (float*)(Mbuf + 65536);          // 590 KB [16,9216]
  float* rbuf  = vfull + 147456;                  // [16,96]
  float* wv    = rbuf + 1536;                     // [256]
  float* tbar  = wv + 256;                        // [16,256]

  const float* xin = (const float*)d_in[0];
  const float* wth = (const float*)d_in[1];
  const float* bth = (const float*)d_in[2];
  const float* wph = (const float*)d_in[3];
  const float* bph = (const float*)d_in[4];
  const float* wg  = (const float*)d_in[5];
  const float* bg  = (const float*)d_in[6];
  const float* beta_w = (const float*)d_in[7];
  const float* beta_h = (const float*)d_in[8];
  const float* beta_c = (const float*)d_in[9];

  hipMemcpyAsync(x, xin, TS * sizeof(float), hipMemcpyDeviceToDevice, stream);

  dim3 blk(256);

  // ---- precompute: M = Wtheta^T * Wphi (bf16), wv = Wphi^T * btheta ----
  gemm_k<1,1,1,1,1><<<dim3(4,4,1), blk, 0, stream>>>(wth, wph, (void*)Mbuf, nullptr, nullptr,
      256, 256, 256, 256, 256, 256, 0, 0, 0, 1);
  wv_k<<<1, blk, 0, stream>>>(wph, bth, wv);

  // ================= pass 0 (width), pass 1 (height) =================
  for (int pass = 0; pass < 2; ++pass) {
    // Y = M * x -> big (bf16)
    gemm_k<0,1,1,0,1><<<dim3(144,4,16), blk, 0, stream>>>(Mbuf, x, (void*)big, nullptr, nullptr,
        256, 9216, 256, 256, 9216, 9216, 0, BS, BS, 1);
    // column bias r[b][j]
    vfull_k<<<576, blk, 0, stream>>>(x, wv, vfull);
    rsum_k<<<6, blk, 0, stream>>>(vfull, rbuf, pass);
    // QK: logits[i][j] = sum_{(c,h)} x(k,i) * Y(k,j)
    hipMemsetAsync(attf, 0, (size_t)16 * 9216 * sizeof(float), stream);
    if (pass == 0)
      gemm_k<1,1,0,1,0><<<dim3(2,2,128), blk, 0, stream>>>(x, big, (void*)attf, nullptr, nullptr,
          96, 96, 24576, 96, 96, 96, BS, BS, 9216, 8);
    else
      gemm_k<2,2,0,1,0><<<dim3(2,2,128), blk, 0, stream>>>(x, big, (void*)attf, nullptr, nullptr,
          96, 96, 24576, 0, 0, 96, BS, BS, 9216, 8);
    softmax_k<<<384, blk, 0, stream>>>(attf, attb, 96, 1536, rbuf, nullptr, nullptr);
    // G = Wg*x + bg -> big (overwrites Y)
    gemm_k<0,1,1,1,1><<<dim3(144,4,16), blk, 0, stream>>>(wg, x, (void*)big, bg, nullptr,
        256, 9216, 256, 256, 9216, 9216, 0, BS, BS, 1);
    // PV fused: x += beta * out
    if (pass == 0)
      gemm_k<0,0,2,0,0><<<dim3(384,2,16), blk, 0, stream>>>(attb, big, (void*)x,
          nullptr, beta_w, 96, 24576, 96, 96, 96, 0, 9216, BS, BS, 1);
    else
      gemm_k<0,3,3,0,0><<<dim3(384,2,16), blk, 0, stream>>>(attb, big, (void*)x,
          nullptr, beta_h, 96, 24576, 96, 96, 0, 0, 9216, BS, BS, 1);
  }

  // ================= pass 2 (channel) =================
  // Theta = Wth*x + bth -> big (bf16)
  gemm_k<0,1,1,1,1><<<dim3(144,4,16), blk, 0, stream>>>(wth, x, (void*)big, bth, nullptr,
      256, 9216, 256, 256, 9216, 9216, 0, BS, BS, 1);
  // Z[i][c] = sum_hw Theta[i,hw] * x[c,hw] -> Zbuf (bf16)
  gemm_k<0,0,1,0,1><<<dim3(4,4,16), blk, 0, stream>>>(big, x, (void*)Zbuf, nullptr, nullptr,
      256, 256, 9216, 9216, 9216, 256, BS, BS, 65536, 1);
  // tbar[b][i] = sum_hw Theta[i,hw]
  sum_rows_k<<<1024, blk, 0, stream>>>(big, tbar, 9216, 4096);
  // L = Z * Wphi^T -> attf
  hipMemsetAsync(attf, 0, (size_t)16 * 256 * 256 * sizeof(float), stream);
  gemm_k<0,0,0,0,1><<<dim3(4,4,16), blk, 0, stream>>>(Zbuf, wph, (void*)attf, nullptr, nullptr,
      256, 256, 256, 256, 256, 256, 65536, 0, 65536, 1);
  // softmax with rank-1 term tbar[row]*bphi[col]
  softmax_k<<<1024, blk, 0, stream>>>(attf, attb, 256, 4096, nullptr, tbar, bph);
  // G -> big (overwrites Theta)
  gemm_k<0,1,1,1,1><<<dim3(144,4,16), blk, 0, stream>>>(wg, x, (void*)big, bg, nullptr,
      256, 9216, 256, 256, 9216, 9216, 0, BS, BS, 1);
  // PV: x[i,hw] += beta_c * sum_j att[i,j] G[j,hw]
  gemm_k<0,1,4,0,0><<<dim3(144,4,16), blk, 0, stream>>>(attb, big, (void*)x,
      nullptr, beta_c, 256, 9216, 256, 256, 9216, 9216, 65536, BS, BS, 1);
}

// Round 4
// 1327.131 us; speedup vs baseline: 1.2655x; 1.2655x over previous
//
#include <hip/hip_runtime.h>
#include <hip/hip_bf16.h>

using bf16 = __hip_bfloat16;
using short8 = __attribute__((ext_vector_type(8))) short;
using float4v = __attribute__((ext_vector_type(4))) float;

#define BM 64
#define BN 64
#define BK 32
#define LDSP 40  // padded LDS row (shorts): 80B rows, 16B-aligned, breaks 96B-stride bank aliasing

__device__ inline short f2b(float x) {
  bf16 h = __float2bfloat16(x);
  return __builtin_bit_cast(short, h);
}

// load 8 contiguous elements at element-offset eoff; F32: convert f32->bf16
template<int F32>
__device__ inline short8 ld8e(const void* base, long eoff) {
  short8 r;
  if constexpr (F32) {
    const float* f = (const float*)base + eoff;
    #pragma unroll
    for (int i = 0; i < 8; ++i) r[i] = f2b(f[i]);
  } else {
    r = *(const short8*)((const short*)base + eoff);
  }
  return r;
}

// A flavors: 0: off=m*lda+k ; 1: off=k*lda+m (transpose: strided coalesced loads + b128 write)
//            2: off=(k/96)*9216+m*96+(k%96) (height-chunked direct)
// B flavors: 0: off=n*ldb+k ; 1: off=k*ldb+n (transpose) ; 2: chunked direct
// EPI: 0: f32 atomicAdd C[row*ldc+col]
//      1: bf16 store (+f32 bias[row] if bias)
//      4: f32 x[row*ldc+col] += beta*v   (coalesced fused residual)
template<int AF, int BF, int EPI, int AF32, int BF32>
__global__ __launch_bounds__(256) void gemm_k(
    const void* __restrict__ Ag, const void* __restrict__ Bg,
    void* __restrict__ Cv, const float* __restrict__ bias, const float* __restrict__ betaP,
    int M, int N, int K, int lda, int ldb, int ldc,
    long sA, long sB, long sC, int ksplit, int abdiv)
{
  __shared__ short As[BM][LDSP];
  __shared__ short Bs[BN][LDSP];
  const int t = threadIdx.x;
  const int lane = t & 63;
  const int wave = t >> 6;
  const int wm = (wave >> 1) * 32;
  const int wn = (wave & 1) * 32;
  const int fr = lane & 15;
  const int fq = lane >> 4;
  const int bz = blockIdx.z;
  const int batch = bz / ksplit;
  const int kc = bz - batch * ksplit;
  const int Kc = K / ksplit;
  const int k0 = kc * Kc;
  const int tm0 = blockIdx.y * BM;
  const int tn0 = blockIdx.x * BN;
  const long abase = (long)(batch / abdiv) * sA;
  const long bbase = (long)batch * sB;

  float4v acc[2][2] = {};

  for (int kk = 0; kk < Kc; kk += BK) {
    const int kbase = k0 + kk;
    // ---- stage A tile: As[m][k] ----
    if constexpr (AF == 0 || AF == 2) {
      int m = t >> 2;
      int kloc = (t & 3) * 8;
      int gk = kbase + kloc;
      short8 v = {};
      if (tm0 + m < M) {
        long off;
        if constexpr (AF == 0) off = abase + (long)(tm0 + m) * lda + gk;
        else                   off = abase + (long)(gk / 96) * 9216 + (long)(tm0 + m) * 96 + (gk % 96);
        v = ld8e<AF32>(Ag, off);
      }
      *(short8*)&As[m][kloc] = v;
    } else {  // AF == 1: lane-coalesced over m; 8 strided loads over k; single b128 write
      int m = t & 63;
      int kg = (t >> 6) * 8;
      short8 v = {};
      if (tm0 + m < M) {
        #pragma unroll
        for (int j = 0; j < 8; ++j) {
          long off = abase + (long)(kbase + kg + j) * lda + tm0 + m;
          v[j] = AF32 ? f2b(((const float*)Ag)[off]) : ((const short*)Ag)[off];
        }
      }
      *(short8*)&As[m][kg] = v;
    }
    // ---- stage B tile: Bs[n][k] ----
    if constexpr (BF == 0 || BF == 2) {
      int n = t >> 2;
      int kloc = (t & 3) * 8;
      int gk = kbase + kloc;
      short8 v = {};
      if (tn0 + n < N) {
        long off;
        if constexpr (BF == 0) off = bbase + (long)(tn0 + n) * ldb + gk;
        else                   off = bbase + (long)(gk / 96) * 9216 + (long)(tn0 + n) * 96 + (gk % 96);
        v = ld8e<BF32>(Bg, off);
      }
      *(short8*)&Bs[n][kloc] = v;
    } else {  // BF == 1
      int n = t & 63;
      int kg = (t >> 6) * 8;
      short8 v = {};
      if (tn0 + n < N) {
        #pragma unroll
        for (int j = 0; j < 8; ++j) {
          long off = bbase + (long)(kbase + kg + j) * ldb + tn0 + n;
          v[j] = BF32 ? f2b(((const float*)Bg)[off]) : ((const short*)Bg)[off];
        }
      }
      *(short8*)&Bs[n][kg] = v;
    }
    __syncthreads();
    short8 af[2], bfv[2];
    #pragma unroll
    for (int i = 0; i < 2; ++i) af[i] = *(const short8*)&As[wm + i * 16 + fr][fq * 8];
    #pragma unroll
    for (int j = 0; j < 2; ++j) bfv[j] = *(const short8*)&Bs[wn + j * 16 + fr][fq * 8];
    #pragma unroll
    for (int i = 0; i < 2; ++i)
      #pragma unroll
      for (int j = 0; j < 2; ++j)
        acc[i][j] = __builtin_amdgcn_mfma_f32_16x16x32_bf16(af[i], bfv[j], acc[i][j], 0, 0, 0);
    __syncthreads();
  }

  float beta = 0.0f;
  if constexpr (EPI >= 2) beta = *betaP;
  const long cb = (long)batch * sC;
  #pragma unroll
  for (int i = 0; i < 2; ++i) {
    #pragma unroll
    for (int j = 0; j < 2; ++j) {
      #pragma unroll
      for (int r = 0; r < 4; ++r) {
        int row = tm0 + wm + i * 16 + fq * 4 + r;
        int col = tn0 + wn + j * 16 + fr;
        if (row < M && col < N) {
          float v = acc[i][j][r];
          if constexpr (EPI == 0) {
            atomicAdd((float*)Cv + cb + (long)row * ldc + col, v);
          } else if constexpr (EPI == 1) {
            if (bias) v += bias[row];
            ((short*)Cv)[cb + (long)row * ldc + col] = f2b(v);
          } else {
            float* xp = (float*)Cv;
            xp[cb + (long)row * ldc + col] += beta * v;
          }
        }
      }
    }
  }
}

// softmax over n cols; logits' = in[row][c] (+ addj[b*n+c]) (+ rowv[row]*colv[c]); out bf16
__global__ __launch_bounds__(256) void softmax_k(
    const float* __restrict__ in, short* __restrict__ out, int n, int rows,
    const float* __restrict__ addj, const float* __restrict__ rowv,
    const float* __restrict__ colv)
{
  int wave = threadIdx.x >> 6;
  int lane = threadIdx.x & 63;
  int row = blockIdx.x * 4 + wave;
  if (row >= rows) return;
  int b = row / n;
  const float* r = in + (long)row * n;
  float rv = rowv ? rowv[row] : 0.0f;
  float vals[4];
  float m = -1e30f;
  #pragma unroll
  for (int i = 0; i < 4; ++i) {
    int c = lane + i * 64;
    float v = -1e30f;
    if (c < n) {
      v = r[c];
      if (addj) v += addj[(long)b * n + c];
      if (colv) v += rv * colv[c];
    }
    vals[i] = v;
    m = fmaxf(m, v);
  }
  #pragma unroll
  for (int off = 32; off > 0; off >>= 1) m = fmaxf(m, __shfl_xor(m, off));
  float s = 0.0f;
  #pragma unroll
  for (int i = 0; i < 4; ++i) {
    int c = lane + i * 64;
    float e = (c < n) ? __expf(vals[i] - m) : 0.0f;
    vals[i] = e;
    s += e;
  }
  #pragma unroll
  for (int off = 32; off > 0; off >>= 1) s += __shfl_xor(s, off);
  float inv = 1.0f / s;
  #pragma unroll
  for (int i = 0; i < 4; ++i) {
    int c = lane + i * 64;
    if (c < n) out[(long)row * n + c] = f2b(vals[i] * inv);
  }
}

// dst[row] = sum_k bf16 src[row*rowlen+k]
__global__ __launch_bounds__(256) void sum_rows_k(
    const short* __restrict__ src, float* __restrict__ dst, int rowlen, int nrows)
{
  int wave = threadIdx.x >> 6;
  int lane = threadIdx.x & 63;
  int row = blockIdx.x * 4 + wave;
  if (row >= nrows) return;
  const short* p = src + (long)row * rowlen;
  float s = 0.0f;
  for (int k = lane; k < rowlen; k += 64)
    s += __bfloat162float(__builtin_bit_cast(bf16, p[k]));
  #pragma unroll
  for (int off = 32; off > 0; off >>= 1) s += __shfl_xor(s, off);
  if (lane == 0) dst[row] = s;
}

// wv[c] = sum_o btheta[o] * Wphi[o*256+c]
__global__ __launch_bounds__(256) void wv_k(
    const float* __restrict__ wphi, const float* __restrict__ btheta, float* __restrict__ wv)
{
  int c = threadIdx.x;
  float s = 0.0f;
  for (int o = 0; o < 256; ++o) s += btheta[o] * wphi[o * 256 + c];
  wv[c] = s;
}

// vfull[b][hw] = sum_c wv[c] * x[b][c*9216+hw]
__global__ __launch_bounds__(256) void vfull_k(
    const float* __restrict__ x, const float* __restrict__ wv, float* __restrict__ vf)
{
  long idx = (long)blockIdx.x * 256 + threadIdx.x;
  int b = (int)(idx / 9216);
  int hw = (int)(idx % 9216);
  const float* p = x + (long)b * 2359296 + hw;
  float s = 0.0f;
  for (int c = 0; c < 256; ++c) s += wv[c] * p[(long)c * 9216];
  vf[idx] = s;
}

// axis 0 (width): r[b][j]=sum_h vf[b][h*96+j]; axis 1 (height): r[b][j]=sum_w vf[b][j*96+w]
__global__ __launch_bounds__(256) void rsum_k(
    const float* __restrict__ vf, float* __restrict__ r, int axis)
{
  int idx = blockIdx.x * 256 + threadIdx.x;
  int b = idx / 96;
  int j = idx % 96;
  const float* p = vf + (long)b * 9216;
  float s = 0.0f;
  if (axis == 0) { for (int h = 0; h < 96; ++h) s += p[h * 96 + j]; }
  else           { for (int w = 0; w < 96; ++w) s += p[j * 96 + w]; }
  r[idx] = s;
}

extern "C" void kernel_launch(void* const* d_in, const int* in_sizes, int n_in,
                              void* d_out, int out_size, void* d_ws, size_t ws_size,
                              hipStream_t stream)
{
  const long TS = 37748736L;   // 16*256*96*96
  const long BS = 2359296L;    // 256*96*96

  float* x = (float*)d_out;                       // f32 state, updated in place
  short* big   = (short*)d_ws;                    // 75.5 MB bf16: Y / Theta / G
  float* attf  = (float*)(big + TS);              // 4 MB logits
  short* attb  = (short*)(attf + 1048576);        // 2 MB bf16 softmaxed att
  float* Zf    = (float*)(attb + 1048576);        // 4 MB f32 [16,256,256]
  short* Mbuf  = (short*)(Zf + 1048576);          // 128 KB bf16 [256,256]
  float* vfull = (float*)(Mbuf + 65536);          // 590 KB [16,9216]
  float* rbuf  = vfull + 147456;                  // [16,96]
  float* wv    = rbuf + 1536;                     // [256]
  float* tbar  = wv + 256;                        // [16,256]

  const float* xin = (const float*)d_in[0];
  const float* wth = (const float*)d_in[1];
  const float* bth = (const float*)d_in[2];
  const float* wph = (const float*)d_in[3];
  const float* bph = (const float*)d_in[4];
  const float* wg  = (const float*)d_in[5];
  const float* bg  = (const float*)d_in[6];
  const float* beta_w = (const float*)d_in[7];
  const float* beta_h = (const float*)d_in[8];
  const float* beta_c = (const float*)d_in[9];

  hipMemcpyAsync(x, xin, TS * sizeof(float), hipMemcpyDeviceToDevice, stream);

  dim3 blk(256);

  // ---- precompute: M = Wtheta^T * Wphi (bf16), wv = Wphi^T * btheta ----
  gemm_k<1,1,1,1,1><<<dim3(4,4,1), blk, 0, stream>>>(wth, wph, (void*)Mbuf, nullptr, nullptr,
      256, 256, 256, 256, 256, 256, 0, 0, 0, 1, 1);
  wv_k<<<1, blk, 0, stream>>>(wph, bth, wv);

  // ================= pass 0 (width), pass 1 (height) =================
  for (int pass = 0; pass < 2; ++pass) {
    // Y = M * x -> big (bf16)
    gemm_k<0,1,1,0,1><<<dim3(144,4,16), blk, 0, stream>>>(Mbuf, x, (void*)big, nullptr, nullptr,
        256, 9216, 256, 256, 9216, 9216, 0, BS, BS, 1, 1);
    // column bias r[b][j]
    vfull_k<<<576, blk, 0, stream>>>(x, wv, vfull);
    rsum_k<<<6, blk, 0, stream>>>(vfull, rbuf, pass);
    // QK: logits[i][j] = sum_{(c,axis)} x(k,i) * Y(k,j)   (split-K 16)
    hipMemsetAsync(attf, 0, (size_t)16 * 9216 * sizeof(float), stream);
    if (pass == 0)
      gemm_k<1,1,0,1,0><<<dim3(2,2,256), blk, 0, stream>>>(x, big, (void*)attf, nullptr, nullptr,
          96, 96, 24576, 96, 96, 96, BS, BS, 9216, 16, 1);
    else
      gemm_k<2,2,0,1,0><<<dim3(2,2,256), blk, 0, stream>>>(x, big, (void*)attf, nullptr, nullptr,
          96, 96, 24576, 0, 0, 96, BS, BS, 9216, 16, 1);
    softmax_k<<<384, blk, 0, stream>>>(attf, attb, 96, 1536, rbuf, nullptr, nullptr);
    // G = Wg*x + bg -> big (overwrites Y)
    gemm_k<0,1,1,1,1><<<dim3(144,4,16), blk, 0, stream>>>(wg, x, (void*)big, bg, nullptr,
        256, 9216, 256, 256, 9216, 9216, 0, BS, BS, 1, 1);
    // PV fused x += beta*out, coalesced epilogues
    if (pass == 0)
      // C[m=(c,h)][n=w] = sum_k G[m,k] att[n,k];  x[b*BS + m*96 + n] += beta*v
      gemm_k<0,0,4,0,0><<<dim3(2,384,16), blk, 0, stream>>>(big, attb, (void*)x,
          nullptr, beta_w, 24576, 96, 96, 96, 96, 96, BS, 9216, BS, 1, 1);
    else
      // batched over (b,c): C[m=h][n=w] = sum_k att[m,k] G_c[k*96+n]
      gemm_k<0,1,4,0,0><<<dim3(2,2,4096), blk, 0, stream>>>(attb, big, (void*)x,
          nullptr, beta_h, 96, 96, 96, 96, 96, 96, 9216, 9216, 9216, 1, 256);
  }

  // ================= pass 2 (channel) =================
  // Theta = Wth*x + bth -> big (bf16)
  gemm_k<0,1,1,1,1><<<dim3(144,4,16), blk, 0, stream>>>(wth, x, (void*)big, bth, nullptr,
      256, 9216, 256, 256, 9216, 9216, 0, BS, BS, 1, 1);
  // Z[i][c] = sum_hw Theta[i,hw] * x[c,hw] -> Zf (f32, split-K 4)
  hipMemsetAsync(Zf, 0, (size_t)16 * 256 * 256 * sizeof(float), stream);
  gemm_k<0,0,0,0,1><<<dim3(4,4,64), blk, 0, stream>>>(big, x, (void*)Zf, nullptr, nullptr,
      256, 256, 9216, 9216, 9216, 256, BS, BS, 65536, 4, 1);
  // tbar[b][i] = sum_hw Theta[i,hw]
  sum_rows_k<<<1024, blk, 0, stream>>>(big, tbar, 9216, 4096);
  // L = Z * Wphi^T -> attf
  hipMemsetAsync(attf, 0, (size_t)16 * 256 * 256 * sizeof(float), stream);
  gemm_k<0,0,0,1,1><<<dim3(4,4,16), blk, 0, stream>>>(Zf, wph, (void*)attf, nullptr, nullptr,
      256, 256, 256, 256, 256, 256, 65536, 0, 65536, 1, 1);
  // softmax with rank-1 term tbar[row]*bphi[col]
  softmax_k<<<1024, blk, 0, stream>>>(attf, attb, 256, 4096, nullptr, tbar, bph);
  // G -> big (overwrites Theta)
  gemm_k<0,1,1,1,1><<<dim3(144,4,16), blk, 0, stream>>>(wg, x, (void*)big, bg, nullptr,
      256, 9216, 256, 256, 9216, 9216, 0, BS, BS, 1, 1);
  // PV: x[i,hw] += beta_c * sum_j att[i,j] G[j,hw]
  gemm_k<0,1,4,0,0><<<dim3(144,4,16), blk, 0, stream>>>(attb, big, (void*)x,
      nullptr, beta_c, 256, 9216, 256, 256, 9216, 9216, 65536, BS, BS, 1, 1);
}